// Round 31
// baseline (318.327 us; speedup 1.0000x reference)
//
#include <hip/hip_runtime.h>
#include <math.h>

// Problem constants (reference: B=16, N=M=4096, D=3)
#define BB 16
#define NP 4096
#define TOTAL (BB * NP)        // 65536 points per cloud
#define BLKS_PER_DIR (BB * 16) // 256 blocks of 256 threads per direction

// Pack (x,y,z) into float4 {x,y,z,|p|^2}.
// |p|^2 replicates np.einsum('bnd,bnd->bn', x, x): npyv masked-muladd tail
// (count=3): single-rounded squares p0,p1,p2 into a zero accumulator, then
// horizontal pairwise fold (identical on SSE2/AVX2/AVX512 reduce paths):
//   sq = (x*x + z*z) + y*y          [FOLD]   -- no FMA (contract off)
__global__ __launch_bounds__(256) void pack_kernel(const float* __restrict__ pts,
                                                   float4* __restrict__ out,
                                                   int total) {
#pragma clang fp contract(off)
    int i = blockIdx.x * blockDim.x + threadIdx.x;
    if (i >= total) return;
    float x = pts[i * 3 + 0];
    float y = pts[i * 3 + 1];
    float z = pts[i * 3 + 2];
    float sq = (x * x + z * z) + y * y;        // npyv FOLD order
    out[i] = make_float4(x, y, z, sq);
}

// One thread per query; scan all NP candidates of the same batch.
// Reference model (31-round elimination): einsum-for-norms +
// matmul-for-cross mirror:
//   sq    : einsum('bnd,bnd->bn') = FOLD (x2+z2)+y2            [NEW axis]
//   inner : matmul (cblas sgemm K=3): zeroed acc, ascending-k FMA:
//           fma(z,pz, fma(y,py, x*px))
//   d     : literal C1 transliteration fl( fl(s1+s2) - 2*inner )
// Strict < with ascending j -> first-occurrence argmin.
// Direction 2 bitwise identical under role swap (fma products commute,
// C1 add commutes bitwise).
__global__ __launch_bounds__(256) void nn_all_kernel(const float4* __restrict__ p1,
                                                     const float4* __restrict__ p2,
                                                     float* __restrict__ out) {
#pragma clang fp contract(off)
    int blk = blockIdx.x;
    const float4* qp;
    const float4* cp;
    float* dbase;
    float* ibase;
    if (blk < BLKS_PER_DIR) {
        qp = p1; cp = p2; dbase = out; ibase = out + 2 * TOTAL;
    } else {
        blk -= BLKS_PER_DIR;
        qp = p2; cp = p1; dbase = out + TOTAL; ibase = out + 3 * TOTAL;
    }
    int b = blk >> 4;                          // 16 blocks of 256 per batch
    int i = ((blk & 15) << 8) + threadIdx.x;
    float4 q = qp[b * NP + i];
    const float4* __restrict__ c = cp + b * NP;

    float best = INFINITY;
    int bi = 0;
    #pragma unroll 8
    for (int j = 0; j < NP; ++j) {
        float4 p = c[j];                       // wave-uniform candidate
        float inner = __builtin_fmaf(q.z, p.z,
                      __builtin_fmaf(q.y, p.y, q.x * p.x));   // asc-FMA
        float d = (q.w + p.w) - 2.0f * inner;  // C1: fl(s1+s2) first
        if (d < best) { best = d; bi = j; }    // strict < -> first occurrence
    }
    dbase[b * NP + i] = best;
    ibase[b * NP + i] = (float)bi;             // idx stored as float32 value
}

extern "C" void kernel_launch(void* const* d_in, const int* in_sizes, int n_in,
                              void* d_out, int out_size, void* d_ws, size_t ws_size,
                              hipStream_t stream) {
    const float* in1 = (const float*)d_in[0];   // (B, N, 3)
    const float* in2 = (const float*)d_in[1];   // (B, M, 3)
    float* out = (float*)d_out;                 // [dist1 | dist2 | idx1 | idx2]

    // Workspace: two packed float4 arrays (1 MB each)
    float4* p1 = (float4*)d_ws;
    float4* p2 = p1 + TOTAL;

    pack_kernel<<<(TOTAL + 255) / 256, 256, 0, stream>>>(in1, p1, TOTAL);
    pack_kernel<<<(TOTAL + 255) / 256, 256, 0, stream>>>(in2, p2, TOTAL);

    nn_all_kernel<<<2 * BLKS_PER_DIR, 256, 0, stream>>>(p1, p2, out);
}